// Round 1
// 266.953 us; speedup vs baseline: 1.0013x; 1.0013x over previous
//
#include <hip/hip_runtime.h>
#include <math.h>

#define HW_     (1024 * 1024)
#define NPIX    (4 * HW_)               // 4,194,304 pixels
#define NG      (NPIX / 4)              // 1,048,576 float4 groups
#define NSETS   64
#define ACC_STRIDE 32                   // doubles/set: 0..7 sx, 8..15 sy, 16..23 cnt, 24 spw, 25 sxx
#define BLOCK_  256
#define GRID1   (NG / BLOCK_)           // 4096 blocks, one float4-group per thread

// fast pow for x>0: v_log_f32 (log2) + v_mul + v_exp_f32 (exp2)
__device__ __forceinline__ float fast_pow_pos(float x, float p) {
    return __builtin_amdgcn_exp2f(p * __builtin_amdgcn_logf(x));
}

// One float4 group (4 consecutive pixels) per thread. Straight-line body:
// all 14 independent 16B loads are issued before any use so the wave keeps
// ~14 KB in flight (VGPR budget 128 via __launch_bounds__(256,4)).
__global__ __launch_bounds__(BLOCK_, 4) void pass1_kernel(
    const float* __restrict__ x, const float* __restrict__ y,
    const float* __restrict__ mk, double* __restrict__ acc)
{
    const int g  = blockIdx.x * BLOCK_ + threadIdx.x;
    const int p0 = g << 2;
    const int b  = p0 >> 20;            // HW_ = 2^20
    const int hw = p0 & (HW_ - 1);

    const size_t xb = (size_t)(b * 3) * HW_ + hw;
    const size_t mb = (size_t)(b * 8) * HW_ + hw;

    // ---- 14 independent vector loads (MLP) ----
    const float4 x0 = *(const float4*)(x + xb);
    const float4 x1 = *(const float4*)(x + xb + HW_);
    const float4 x2 = *(const float4*)(x + xb + 2 * (size_t)HW_);
    const float4 y0 = *(const float4*)(y + xb);
    const float4 y1 = *(const float4*)(y + xb + HW_);
    const float4 y2 = *(const float4*)(y + xb + 2 * (size_t)HW_);
    const float4 m0 = *(const float4*)(mk + mb);
    const float4 m1 = *(const float4*)(mk + mb + 1 * (size_t)HW_);
    const float4 m2 = *(const float4*)(mk + mb + 2 * (size_t)HW_);
    const float4 m3 = *(const float4*)(mk + mb + 3 * (size_t)HW_);
    const float4 m4 = *(const float4*)(mk + mb + 4 * (size_t)HW_);
    const float4 m5 = *(const float4*)(mk + mb + 5 * (size_t)HW_);
    const float4 m6 = *(const float4*)(mk + mb + 6 * (size_t)HW_);
    const float4 m7 = *(const float4*)(mk + mb + 7 * (size_t)HW_);

    float sx[8], sy[8], sc[8];
#pragma unroll
    for (int l = 0; l < 8; ++l) { sx[l] = 0.f; sy[l] = 0.f; sc[l] = 0.f; }
    float spw = 0.f, sxx = 0.f;

    const float inv3 = 1.0f / 3.0f;     // mul, not the v_div_* sequence

    // strict >: first occurrence wins (jnp.argmax tie-break)
#define PIX(F)                                                              \
    {                                                                       \
        const float xav = (x0.F + x1.F + x2.F) * inv3;                      \
        const float yav = (y0.F + y1.F + y2.F) * inv3;                      \
        float best = m0.F; int bi = 0;                                      \
        if (m1.F > best) { best = m1.F; bi = 1; }                           \
        if (m2.F > best) { best = m2.F; bi = 2; }                           \
        if (m3.F > best) { best = m3.F; bi = 3; }                           \
        if (m4.F > best) { best = m4.F; bi = 4; }                           \
        if (m5.F > best) { best = m5.F; bi = 5; }                           \
        if (m6.F > best) { best = m6.F; bi = 6; }                           \
        if (m7.F > best) { best = m7.F; bi = 7; }                           \
        _Pragma("unroll")                                                   \
        for (int l = 0; l < 8; ++l) {                                       \
            const bool p = (bi == l);                                       \
            sx[l] += p ? xav : 0.0f;                                        \
            sy[l] += p ? yav : 0.0f;                                        \
            sc[l] += p ? 1.0f : 0.0f;                                       \
        }                                                                   \
        spw += fast_pow_pos(xav, yav);  /* xav>0: mean of uniforms */       \
        sxx += xav * xav;                                                   \
    }

    PIX(x) PIX(y) PIX(z) PIX(w)
#undef PIX

    // ---- wave64 shuffle reduction of the 26 accumulators ----
#pragma unroll
    for (int off = 32; off > 0; off >>= 1) {
#pragma unroll
        for (int l = 0; l < 8; ++l) {
            sx[l] += __shfl_down(sx[l], off);
            sy[l] += __shfl_down(sy[l], off);
            sc[l] += __shfl_down(sc[l], off);
        }
        spw += __shfl_down(spw, off);
        sxx += __shfl_down(sxx, off);
    }
    __shared__ float red[4][26];
    const int wave = threadIdx.x >> 6, lane = threadIdx.x & 63;
    if (lane == 0) {
#pragma unroll
        for (int l = 0; l < 8; ++l) {
            red[wave][l]      = sx[l];
            red[wave][8 + l]  = sy[l];
            red[wave][16 + l] = sc[l];
        }
        red[wave][24] = spw;
        red[wave][25] = sxx;
    }
    __syncthreads();
    if (threadIdx.x < 26) {
        float t = red[0][threadIdx.x] + red[1][threadIdx.x] +
                  red[2][threadIdx.x] + red[3][threadIdx.x];
        atomicAdd(&acc[(blockIdx.x & (NSETS - 1)) * ACC_STRIDE + threadIdx.x],
                  (double)t);
    }
}

// ---- finalize: all three losses in f64, write 3 floats ----
__global__ void finalize_kernel(const double* __restrict__ acc,
                                float* __restrict__ out)
{
    __shared__ double sh[26];
    int t = threadIdx.x;
    if (t < 26) {
        double s = 0.0;
        for (int k = 0; k < NSETS; ++k) s += acc[k * ACC_STRIDE + t];
        sh[t] = s;
    }
    __syncthreads();
    if (t == 0) {
        const double invN = 1.0 / (double)NPIX;
        double l1 = sh[24];       // sum of pow over on-mask pixels
        double l3 = sh[25];       // sum of xa^2
        double l2 = 0.0;
        for (int l = 0; l < 8; ++l) {
            double SX  = sh[l];
            double XA  = SX * invN;
            double YA  = sh[8 + l] * invN;
            double cnt = sh[16 + l];
            double pw  = pow(XA, YA);
            l2 += pw;
            l1 += ((double)NPIX - cnt) * pw;          // off-mask pow terms
            l3 += cnt * XA * XA - 2.0 * XA * SX;      // per-label variance cross terms
        }
        out[0] = (float)(l1 * invN);
        out[1] = (float)l2;
        out[2] = (float)(l3 * invN);
    }
}

extern "C" void kernel_launch(void* const* d_in, const int* in_sizes, int n_in,
                              void* d_out, int out_size, void* d_ws, size_t ws_size,
                              hipStream_t stream)
{
    const float* x  = (const float*)d_in[0];
    const float* y  = (const float*)d_in[1];
    const float* mk = (const float*)d_in[2];
    float* out = (float*)d_out;

    double* acc = (double*)d_ws;                    // 64*32*8 = 16 KB
    (void)hipMemsetAsync(acc, 0, NSETS * ACC_STRIDE * 8, stream);

    pass1_kernel<<<GRID1, BLOCK_, 0, stream>>>(x, y, mk, acc);
    finalize_kernel<<<1, 64, 0, stream>>>(acc, out);
}